// Round 6
// baseline (77.617 us; speedup 1.0000x reference)
//
#include <hip/hip_runtime.h>
#include <hip/hip_bf16.h>

#define L_ 30
#define NB 2
#define NN 64
#define NM 64
#define MCH 16

// ws float offsets
#define O_BOP  0        // 128
#define O_WEWK 128      // 4x128
#define O_CK   640      // 30x128
#define O_QS   4480     // 128x128 (q / sqrt(dh))
#define O_GT   20864    // ushort[128][168] transposed G (rows e, cols k)
#define O_CTR  32768    // unsigned ready-counter (memset to 0 each call)

typedef __attribute__((ext_vector_type(8))) short short8;
typedef __attribute__((ext_vector_type(4))) float f32x4;

__device__ __forceinline__ unsigned short f2b(float v) {
    union { float f; unsigned int u; } x; x.f = v;
    unsigned int u = x.u + 0x7FFFu + ((x.u >> 16) & 1u);
    return (unsigned short)(u >> 16);
}
__device__ __forceinline__ float b2f(unsigned short s) {
    union { unsigned int u; float f; } x; x.u = ((unsigned int)s) << 16; return x.f;
}
__device__ __forceinline__ float dot4(float4 a, float4 b) {
    return a.x*b.x + a.y*b.y + a.z*b.z + a.w*b.w;
}

// 640 blocks: 0..127 = pre (one output column e each), 128..639 = main.
// Handoff: producers release via fence+atomicAdd; consumers poll with
// device-scope atomic LOAD (not RMW — R5's RMW spin-storm serialized ~70us).
// Co-residency: launch_bounds(256,3) => >=3 blocks/CU = 768 slots >= 640.
__global__ __launch_bounds__(256, 3)
void k_all(const float* __restrict__ agent, const float* __restrict__ lane,
           const float* __restrict__ We,  const float* __restrict__ be,
           const float* __restrict__ Wa,  const float* __restrict__ ba,
           const float* __restrict__ pe,
           const float* __restrict__ Wq,  const float* __restrict__ bq,
           const float* __restrict__ Wk,  const float* __restrict__ bk,
           const float* __restrict__ Wv,  const float* __restrict__ bv,
           const float* __restrict__ Wo,  const float* __restrict__ bo,
           const float* __restrict__ Wp,  const float* __restrict__ bp,
           float* __restrict__ ws, float* __restrict__ out) {

    __shared__ __align__(16) char smem[21824];   // overlay: pre 20.1KB | main 21.8KB
    const int t = threadIdx.x;
    const int bid = blockIdx.x;
    unsigned* ctr = (unsigned*)(ws + O_CTR);

    if (bid < 128) {
        // ---------------- PRE: one output column e ----------------
        const int e = bid;
        float* pb     = (float*)smem;
        float* wp_s   = pb;           // 128
        float* wq_s   = pb + 128;     // 128
        float* wk_s   = pb + 256;     // 128
        float* wop_s  = pb + 384;     // 128
        float* wawq_s = pb + 512;     // 12
        float* misc   = pb + 524;     // [0]=bqq [1..4]=dbv
        float* pesum  = pb + 532;     // 30*132
        float* wvop   = pb + 4492;    // 4*132

        if (t < 128) { wp_s[t] = Wp[t*128+e]; wq_s[t] = Wq[t*128+e]; }
        else         { int d = t-128; wk_s[d] = Wk[d*128+e]; }
        for (int i = t; i < 30*128; i += 256) {
            int l = i >> 7, d = i & 127;
            pesum[l*132+d] = be[d] + pe[l*128+d];
        }
        __syncthreads();

        if (t < 128) {
            const float4* wo  = (const float4*)(Wo + t*128);
            const float4* wp4 = (const float4*)wp_s;
            float a = 0.f;
            #pragma unroll 8
            for (int i = 0; i < 32; ++i) a += dot4(wo[i], wp4[i]);
            wop_s[t] = a;
        } else if (t < 158) {
            int l = t - 128;
            const float4* pl  = (const float4*)(pesum + l*132);
            const float4* wk4 = (const float4*)wk_s;
            float a = bk[e];
            #pragma unroll 8
            for (int i = 0; i < 32; ++i) a += dot4(pl[i], wk4[i]);
            ws[O_CK + l*128 + e] = a;
        } else if (t < 170) {
            int f = t - 158;
            const float4* wa4 = (const float4*)(Wa + f*128);
            const float4* wq4 = (const float4*)wq_s;
            float a = 0.f;
            #pragma unroll 8
            for (int i = 0; i < 32; ++i) a += dot4(wa4[i], wq4[i]);
            wawq_s[f] = a;
        } else if (t == 170) {
            float a = bq[e];
            for (int d = 0; d < 128; ++d) a += ba[d]*wq_s[d];
            misc[0] = a;
        } else if (t >= 172 && t < 176) {
            int j = t - 172;
            const float4* wej = (const float4*)(We + j*128);
            const float4* wk4 = (const float4*)wk_s;
            float a = 0.f;
            #pragma unroll 8
            for (int i = 0; i < 32; ++i) a += dot4(wej[i], wk4[i]);
            ws[O_WEWK + j*128 + e] = a;
        }
        __syncthreads();

        #pragma unroll
        for (int kk = 0; kk < 2; ++kk) {
            int job = t*2 + kk;
            int h = job & 3, d = job >> 2;
            const float4* wv4 = (const float4*)(Wv + d*128 + h*32);
            const float4* wc4 = (const float4*)(wop_s + h*32);
            float a = 0.f;
            #pragma unroll
            for (int i = 0; i < 8; ++i) a += dot4(wv4[i], wc4[i]);
            wvop[h*132 + d] = a;
        }
        if (t < 128) {
            float a = misc[0];
            const float* ag = agent + t*16;
            a += ag[2]*wawq_s[0];
            #pragma unroll
            for (int f = 1; f < 12; ++f) a += ag[4+f]*wawq_s[f];
            ws[O_QS + t*128 + e] = a * 0.17677669529663687f;
        } else if (t < 132) {
            int h = t-128;
            float a = 0.f;
            for (int c = 0; c < 32; ++c) a += bv[h*32+c]*wop_s[h*32+c];
            misc[1+h] = a;
        } else if (t == 132) {
            float a = bp[e];
            for (int c = 0; c < 128; ++c) a += bo[c]*wop_s[c];
            ws[O_BOP + e] = a;
        }
        __syncthreads();

        unsigned short* GT = (unsigned short*)(ws + O_GT);
        if (t < 16) {
            int h = t >> 2, j = t & 3;
            const float4* wej = (const float4*)(We + j*128);
            const float4* wv4 = (const float4*)(wvop + h*132);
            float a = 0.f;
            #pragma unroll 8
            for (int i = 0; i < 32; ++i) a += dot4(wej[i], wv4[i]);
            GT[e*168 + t] = f2b(a);
        } else if (t < 136) {
            int r = t-16; int h = r/30, l = r - h*30;
            const float4* pl  = (const float4*)(pesum + l*132);
            const float4* wv4 = (const float4*)(wvop + h*132);
            float a = misc[1+h];
            #pragma unroll 8
            for (int i = 0; i < 32; ++i) a += dot4(pl[i], wv4[i]);
            GT[e*168 + t] = f2b(a);
        } else if (t < 168) {
            GT[e*168 + t] = 0;
        }

        // release: all writes visible device-wide, then count up
        __syncthreads();
        __threadfence();
        if (t == 0) atomicAdd(ctr, 1u);
        return;
    }

    // ---------------- MAIN ----------------
    const int bid2 = bid - 128;
    const int bn = bid2 >> 2;
    const int m0 = (bid2 & 3) * MCH;
    const int b = bn >> 6;

    float (*ScE)[124] = (float (*)[124])smem;                         // edges f32 [m][l*4+k]
    float (*ScS)[124] = (float (*)[124])(smem + 7936);                // scores [m][h*30+l]
    unsigned short (*WcB)[168] = (unsigned short (*)[168])(smem + 15872);
    float* u_s = (float*)(smem + 21248);                              // 16
    float* c_s = (float*)(smem + 21312);                              // 120

    // prefix (independent of pre): WcB tail zero + edge geometry
    for (int i = t; i < 16*24; i += 256) {
        int m = i / 24;
        WcB[m][136 + (i - m*24)] = 0;
    }
    const float ax  = agent[bn*16+0], ay = agent[bn*16+1];
    const float as_ = agent[bn*16+3], ac = agent[bn*16+4];
    const float f1 = (ax==0.f && ay==0.f && as_==0.f && ac==0.f) ? 0.f : 1.f;
    for (int job = t; job < MCH*30; job += 256) {
        int m = job / 30, l = job - m*30;
        const float* lp = lane + (size_t)((b*NM + m0 + m)*L_ + l)*4;
        float4 lv = *(const float4*)lp;
        float f2 = (lv.x==0.f && lv.y==0.f && lv.z==0.f && lv.w==0.f) ? 0.f : 1.f;
        float f = f1 * f2;
        float dx = lv.x - ax, dy = lv.y - ay;
        ScE[m][l*4+0] = (ac*dx + as_*dy) * 0.1f * f;
        ScE[m][l*4+1] = (ac*dy - as_*dx) * 0.1f * f;
        ScE[m][l*4+2] = (lv.z*ac - lv.w*as_) * f;
        ScE[m][l*4+3] = (lv.w*ac + lv.z*as_) * f;
    }

    // acquire: poll with device-scope atomic LOAD (no RMW storm)
    if (t == 0) {
        while (__hip_atomic_load(ctr, __ATOMIC_RELAXED, __HIP_MEMORY_SCOPE_AGENT) < 128u) {
            __builtin_amdgcn_s_sleep(16);
        }
    }
    __syncthreads();
    __threadfence();   // agent-scope acquire: invalidate stale L1/L2 before reading ws

    // prefetch G fragments + bias to registers (hide L2/L3 latency under M0..M3)
    const unsigned short* GT = (const unsigned short*)(ws + O_GT);
    const int lane_id = t & 63;
    const int wv = t >> 6;
    const int frm = lane_id & 15;
    const int kg  = lane_id >> 4;
    const int e0 = wv*32 + frm;
    short8 g0[5], g1[5];
    #pragma unroll
    for (int i = 0; i < 5; ++i) {
        g0[i] = *(const short8*)&GT[(size_t)e0*168 + i*32 + kg*8];
        g1[i] = *(const short8*)&GT[(size_t)(e0+16)*168 + i*32 + kg*8];
    }
    const float bb0 = ws[O_BOP + e0];
    const float bb1 = ws[O_BOP + e0 + 16];

    // M0: per-agent u (4x4) and c (4x30)
    if (t < 136) {
        if (t < 16) {
            int h = t >> 2, j = t & 3;
            const float4* x = (const float4*)(ws + O_WEWK + j*128 + h*32);
            const float4* y = (const float4*)(ws + O_QS + bn*128 + h*32);
            float a = 0.f;
            #pragma unroll
            for (int i = 0; i < 8; ++i) a += dot4(x[i], y[i]);
            u_s[t] = a;
        } else {
            int r = t - 16; int h = r/30, l = r - h*30;
            const float4* x = (const float4*)(ws + O_CK + l*128 + h*32);
            const float4* y = (const float4*)(ws + O_QS + bn*128 + h*32);
            float a = 0.f;
            #pragma unroll
            for (int i = 0; i < 8; ++i) a += dot4(x[i], y[i]);
            c_s[r] = a;
        }
    }
    __syncthreads();

    // M1: scores from stored edges
    for (int job = t; job < MCH*30; job += 256) {
        int m = job / 30, l = job - m*30;
        float rx = ScE[m][l*4+0], ry = ScE[m][l*4+1];
        float rs = ScE[m][l*4+2], rc = ScE[m][l*4+3];
        #pragma unroll
        for (int h = 0; h < 4; ++h) {
            ScS[m][h*30 + l] = rx*u_s[h*4+0] + ry*u_s[h*4+1] + rs*u_s[h*4+2]
                             + rc*u_s[h*4+3] + c_s[h*30+l];
        }
    }
    __syncthreads();

    // M2: softmax, 4 lanes per (m,h), static 8-slot unroll (no scratch)
    {
        const int m = t >> 4, hh = (t >> 2) & 3, s = t & 3;
        float vals[8];
        float mx = -1e30f;
        #pragma unroll
        for (int k = 0; k < 8; ++k) {
            int l = s + 4*k;
            vals[k] = (l < 30) ? ScS[m][hh*30 + l] : -1e30f;
            mx = fmaxf(mx, vals[k]);
        }
        mx = fmaxf(mx, __shfl_xor(mx, 1, 64));
        mx = fmaxf(mx, __shfl_xor(mx, 2, 64));
        float sum = 0.f;
        #pragma unroll
        for (int k = 0; k < 8; ++k) {
            float ev = __expf(vals[k] - mx);
            ev = (s + 4*k < 30) ? ev : 0.f;
            vals[k] = ev; sum += ev;
        }
        sum += __shfl_xor(sum, 1, 64);
        sum += __shfl_xor(sum, 2, 64);
        float inv = 1.f / sum;
        #pragma unroll
        for (int k = 0; k < 8; ++k) {
            int l = s + 4*k;
            if (l < 30) WcB[m][16 + hh*30 + l] = f2b(vals[k]*inv);
        }
    }
    __syncthreads();

    // M3: we4 -> bf16 into WcB[m][h*4+j]
    {
        int m = t >> 4, i = t & 15;
        int hh = i >> 2, j = i & 3;
        float a = 0.f;
        for (int l = 0; l < 30; ++l)
            a += b2f(WcB[m][16 + hh*30 + l]) * ScE[m][l*4 + j];
        WcB[m][i] = f2b(a);
    }
    __syncthreads();

    // M4: OUT[16x128] = WcB[16x160] @ G[160x128] via MFMA (B from regs)
    {
        f32x4 acc0 = {bb0, bb0, bb0, bb0};
        f32x4 acc1 = {bb1, bb1, bb1, bb1};
        #pragma unroll
        for (int i = 0; i < 5; ++i) {
            short8 a = *(const short8*)&WcB[frm][i*32 + kg*8];
            acc0 = __builtin_amdgcn_mfma_f32_16x16x32_bf16(a, g0[i], acc0, 0, 0, 0);
            acc1 = __builtin_amdgcn_mfma_f32_16x16x32_bf16(a, g1[i], acc1, 0, 0, 0);
        }
        float* ob = out + ((size_t)(bn*NM + m0))*128;
        #pragma unroll
        for (int r = 0; r < 4; ++r) {
            int m = kg*4 + r;
            ob[m*128 + e0]      = acc0[r];
            ob[m*128 + e0 + 16] = acc1[r];
        }
    }
}

extern "C" void kernel_launch(void* const* d_in, const int* in_sizes, int n_in,
                              void* d_out, int out_size, void* d_ws, size_t ws_size,
                              hipStream_t stream) {
    const float* agent = (const float*)d_in[0];
    const float* lane  = (const float*)d_in[1];
    const float* We = (const float*)d_in[2];
    const float* be = (const float*)d_in[3];
    const float* Wa = (const float*)d_in[4];
    const float* ba = (const float*)d_in[5];
    const float* pe = (const float*)d_in[6];
    const float* Wq = (const float*)d_in[7];
    const float* bq = (const float*)d_in[8];
    const float* Wk = (const float*)d_in[9];
    const float* bk = (const float*)d_in[10];
    const float* Wv = (const float*)d_in[11];
    const float* bv = (const float*)d_in[12];
    const float* Wo = (const float*)d_in[13];
    const float* bo = (const float*)d_in[14];
    const float* Wp = (const float*)d_in[15];
    const float* bp = (const float*)d_in[16];
    float* ws  = (float*)d_ws;
    float* out = (float*)d_out;

    hipMemsetAsync((char*)d_ws + O_CTR*sizeof(float), 0, sizeof(unsigned), stream);
    hipLaunchKernelGGL(k_all, dim3(128 + NB*NN*4), dim3(256), 0, stream,
                       agent, lane, We, be, Wa, ba, pe, Wq, bq, Wk, bk, Wv, bv,
                       Wo, bo, Wp, bp, ws, out);
}

// Round 7
// 25.556 us; speedup vs baseline: 3.0372x; 3.0372x over previous
//
#include <hip/hip_runtime.h>
#include <hip/hip_bf16.h>

#define L_ 30
#define NB 2
#define NN 64
#define NM 64
#define MCH 16

// ws float offsets
#define O_BOP  0        // 128
#define O_WEWK 128      // 4x128
#define O_CK   640      // 30x128
#define O_QS   4480     // 128x128 (q / sqrt(dh))
#define O_GT   20864    // ushort[128][168] transposed G (rows e, cols k)

typedef __attribute__((ext_vector_type(8))) short short8;
typedef __attribute__((ext_vector_type(4))) float f32x4;

__device__ __forceinline__ unsigned short f2b(float v) {
    union { float f; unsigned int u; } x; x.f = v;
    unsigned int u = x.u + 0x7FFFu + ((x.u >> 16) & 1u);
    return (unsigned short)(u >> 16);
}
__device__ __forceinline__ float b2f(unsigned short s) {
    union { unsigned int u; float f; } x; x.u = ((unsigned int)s) << 16; return x.f;
}
__device__ __forceinline__ float dot4(float4 a, float4 b) {
    return a.x*b.x + a.y*b.y + a.z*b.z + a.w*b.w;
}

// 128 blocks, one output column e each. Column-parallel precompute (proven R4).
__global__ __launch_bounds__(256)
void k_pre(const float* __restrict__ agent,
           const float* __restrict__ We,  const float* __restrict__ be,
           const float* __restrict__ Wa,  const float* __restrict__ ba,
           const float* __restrict__ pe,
           const float* __restrict__ Wq,  const float* __restrict__ bq,
           const float* __restrict__ Wk,  const float* __restrict__ bk,
           const float* __restrict__ Wv,  const float* __restrict__ bv,
           const float* __restrict__ Wo,  const float* __restrict__ bo,
           const float* __restrict__ Wp,  const float* __restrict__ bp,
           float* __restrict__ ws) {
    const int e = blockIdx.x;
    const int t = threadIdx.x;
    __shared__ __align__(16) float pb[5020];
    float* wp_s   = pb;           // 128
    float* wq_s   = pb + 128;     // 128
    float* wk_s   = pb + 256;     // 128
    float* wop_s  = pb + 384;     // 128
    float* wawq_s = pb + 512;     // 12
    float* misc   = pb + 524;     // [0]=bqq [1..4]=dbv
    float* pesum  = pb + 532;     // 30*132
    float* wvop   = pb + 4492;    // 4*132

    if (t < 128) { wp_s[t] = Wp[t*128+e]; wq_s[t] = Wq[t*128+e]; }
    else         { int d = t-128; wk_s[d] = Wk[d*128+e]; }
    for (int i = t; i < 30*128; i += 256) {
        int l = i >> 7, d = i & 127;
        pesum[l*132+d] = be[d] + pe[l*128+d];
    }
    __syncthreads();

    if (t < 128) {
        const float4* wo  = (const float4*)(Wo + t*128);
        const float4* wp4 = (const float4*)wp_s;
        float a = 0.f;
        #pragma unroll 8
        for (int i = 0; i < 32; ++i) a += dot4(wo[i], wp4[i]);
        wop_s[t] = a;
    } else if (t < 158) {
        int l = t - 128;
        const float4* pl  = (const float4*)(pesum + l*132);
        const float4* wk4 = (const float4*)wk_s;
        float a = bk[e];
        #pragma unroll 8
        for (int i = 0; i < 32; ++i) a += dot4(pl[i], wk4[i]);
        ws[O_CK + l*128 + e] = a;
    } else if (t < 170) {
        int f = t - 158;
        const float4* wa4 = (const float4*)(Wa + f*128);
        const float4* wq4 = (const float4*)wq_s;
        float a = 0.f;
        #pragma unroll 8
        for (int i = 0; i < 32; ++i) a += dot4(wa4[i], wq4[i]);
        wawq_s[f] = a;
    } else if (t == 170) {
        float a = bq[e];
        for (int d = 0; d < 128; ++d) a += ba[d]*wq_s[d];
        misc[0] = a;
    } else if (t >= 172 && t < 176) {
        int j = t - 172;
        const float4* wej = (const float4*)(We + j*128);
        const float4* wk4 = (const float4*)wk_s;
        float a = 0.f;
        #pragma unroll 8
        for (int i = 0; i < 32; ++i) a += dot4(wej[i], wk4[i]);
        ws[O_WEWK + j*128 + e] = a;
    }
    __syncthreads();

    #pragma unroll
    for (int kk = 0; kk < 2; ++kk) {
        int job = t*2 + kk;
        int h = job & 3, d = job >> 2;
        const float4* wv4 = (const float4*)(Wv + d*128 + h*32);
        const float4* wc4 = (const float4*)(wop_s + h*32);
        float a = 0.f;
        #pragma unroll
        for (int i = 0; i < 8; ++i) a += dot4(wv4[i], wc4[i]);
        wvop[h*132 + d] = a;
    }
    if (t < 128) {
        float a = misc[0];
        const float* ag = agent + t*16;
        a += ag[2]*wawq_s[0];
        #pragma unroll
        for (int f = 1; f < 12; ++f) a += ag[4+f]*wawq_s[f];
        ws[O_QS + t*128 + e] = a * 0.17677669529663687f;
    } else if (t < 132) {
        int h = t-128;
        float a = 0.f;
        for (int c = 0; c < 32; ++c) a += bv[h*32+c]*wop_s[h*32+c];
        misc[1+h] = a;
    } else if (t == 132) {
        float a = bp[e];
        for (int c = 0; c < 128; ++c) a += bo[c]*wop_s[c];
        ws[O_BOP + e] = a;
    }
    __syncthreads();

    unsigned short* GT = (unsigned short*)(ws + O_GT);
    if (t < 16) {
        int h = t >> 2, j = t & 3;
        const float4* wej = (const float4*)(We + j*128);
        const float4* wv4 = (const float4*)(wvop + h*132);
        float a = 0.f;
        #pragma unroll 8
        for (int i = 0; i < 32; ++i) a += dot4(wej[i], wv4[i]);
        GT[e*168 + t] = f2b(a);
    } else if (t < 136) {
        int r = t-16; int h = r/30, l = r - h*30;
        const float4* pl  = (const float4*)(pesum + l*132);
        const float4* wv4 = (const float4*)(wvop + h*132);
        float a = misc[1+h];
        #pragma unroll 8
        for (int i = 0; i < 32; ++i) a += dot4(pl[i], wv4[i]);
        GT[e*168 + t] = f2b(a);
    } else if (t < 168) {
        GT[e*168 + t] = 0;
    }
}

// 512 blocks. 3 phases / 2 barriers; parallel softmax fused with scores + we4.
__global__ __launch_bounds__(256)
void k_main(const float* __restrict__ agent, const float* __restrict__ lane,
            const float* __restrict__ ws, float* __restrict__ out) {

    __shared__ __align__(16) float ScE[16][124];              // edges f32 [m][l*4+j]
    __shared__ __align__(16) unsigned short WcB[16][168];     // bf16: [0..16) we4, [16..136) w
    __shared__ __align__(16) float uc_s[136];                 // [0..16)=u, [16..136)=c

    const int t = threadIdx.x;
    const int bid = blockIdx.x;
    const int bn = bid >> 2;
    const int m0 = (bid & 3) * MCH;
    const int b = bn >> 6;

    // ---- phase 0: G/bias prefetch (regs) + u/c dots + edge geometry + WcB pad ----
    const unsigned short* GT = (const unsigned short*)(ws + O_GT);
    const int lane_id = t & 63;
    const int wv = t >> 6;
    const int frm = lane_id & 15;
    const int kg  = lane_id >> 4;
    const int e0 = wv*32 + frm;
    short8 g0[5], g1[5];
    #pragma unroll
    for (int i = 0; i < 5; ++i) {
        g0[i] = *(const short8*)&GT[(size_t)e0*168 + i*32 + kg*8];
        g1[i] = *(const short8*)&GT[(size_t)(e0+16)*168 + i*32 + kg*8];
    }
    const float bb0 = ws[O_BOP + e0];
    const float bb1 = ws[O_BOP + e0 + 16];

    for (int i = t; i < 16*24; i += 256) {
        int m = i / 24;
        WcB[m][136 + (i - m*24)] = 0;
    }
    if (t < 136) {
        if (t < 16) {
            int h = t >> 2, j = t & 3;
            const float4* x = (const float4*)(ws + O_WEWK + j*128 + h*32);
            const float4* y = (const float4*)(ws + O_QS + bn*128 + h*32);
            float a = 0.f;
            #pragma unroll
            for (int i = 0; i < 8; ++i) a += dot4(x[i], y[i]);
            uc_s[t] = a;
        } else {
            int r = t - 16; int h = r/30, l = r - h*30;
            const float4* x = (const float4*)(ws + O_CK + l*128 + h*32);
            const float4* y = (const float4*)(ws + O_QS + bn*128 + h*32);
            float a = 0.f;
            #pragma unroll
            for (int i = 0; i < 8; ++i) a += dot4(x[i], y[i]);
            uc_s[t] = a;
        }
    }
    const float ax  = agent[bn*16+0], ay = agent[bn*16+1];
    const float as_ = agent[bn*16+3], ac = agent[bn*16+4];
    const float f1 = (ax==0.f && ay==0.f && as_==0.f && ac==0.f) ? 0.f : 1.f;
    for (int job = t; job < MCH*30; job += 256) {
        int m = job / 30, l = job - m*30;
        const float* lp = lane + (size_t)((b*NM + m0 + m)*L_ + l)*4;
        float4 lv = *(const float4*)lp;
        float f2 = (lv.x==0.f && lv.y==0.f && lv.z==0.f && lv.w==0.f) ? 0.f : 1.f;
        float f = f1 * f2;
        float dx = lv.x - ax, dy = lv.y - ay;
        float4 ev;
        ev.x = (ac*dx + as_*dy) * 0.1f * f;
        ev.y = (ac*dy - as_*dx) * 0.1f * f;
        ev.z = (lv.z*ac - lv.w*as_) * f;
        ev.w = (lv.w*ac + lv.z*as_) * f;
        *(float4*)&ScE[m][l*4] = ev;
    }
    __syncthreads();

    // ---- phase 1: scores + 4-lane softmax + fused we4 ----
    {
        const int m = t >> 4, hh = (t >> 2) & 3, s = t & 3;
        float4 u4 = *(const float4*)&uc_s[hh*4];
        float4 e4[8];
        float sc[8];
        float mx = -1e30f;
        #pragma unroll
        for (int k = 0; k < 8; ++k) {
            int l = s + 4*k;
            if (l < 30) {
                e4[k] = *(const float4*)&ScE[m][l*4];
                sc[k] = e4[k].x*u4.x + e4[k].y*u4.y + e4[k].z*u4.z + e4[k].w*u4.w
                      + uc_s[16 + hh*30 + l];
            } else {
                e4[k] = make_float4(0.f,0.f,0.f,0.f);
                sc[k] = -1e30f;
            }
            mx = fmaxf(mx, sc[k]);
        }
        mx = fmaxf(mx, __shfl_xor(mx, 1, 64));
        mx = fmaxf(mx, __shfl_xor(mx, 2, 64));
        float sum = 0.f;
        float wvv[8];
        #pragma unroll
        for (int k = 0; k < 8; ++k) {
            float evv = __expf(sc[k] - mx);
            evv = (s + 4*k < 30) ? evv : 0.f;
            wvv[k] = evv; sum += evv;
        }
        sum += __shfl_xor(sum, 1, 64);
        sum += __shfl_xor(sum, 2, 64);
        const float inv = 1.f / sum;
        float4 p = make_float4(0.f,0.f,0.f,0.f);
        #pragma unroll
        for (int k = 0; k < 8; ++k) {
            int l = s + 4*k;
            if (l < 30) {
                float w = wvv[k] * inv;
                WcB[m][16 + hh*30 + l] = f2b(w);
                p.x += w * e4[k].x; p.y += w * e4[k].y;
                p.z += w * e4[k].z; p.w += w * e4[k].w;
            }
        }
        p.x += __shfl_xor(p.x, 1, 64); p.y += __shfl_xor(p.y, 1, 64);
        p.z += __shfl_xor(p.z, 1, 64); p.w += __shfl_xor(p.w, 1, 64);
        p.x += __shfl_xor(p.x, 2, 64); p.y += __shfl_xor(p.y, 2, 64);
        p.z += __shfl_xor(p.z, 2, 64); p.w += __shfl_xor(p.w, 2, 64);
        float mine = (s == 0) ? p.x : (s == 1) ? p.y : (s == 2) ? p.z : p.w;
        WcB[m][hh*4 + s] = f2b(mine);
    }
    __syncthreads();

    // ---- phase 2: OUT[16x128] = WcB[16x160] @ G[160x128] via MFMA ----
    {
        f32x4 acc0 = {bb0, bb0, bb0, bb0};
        f32x4 acc1 = {bb1, bb1, bb1, bb1};
        #pragma unroll
        for (int i = 0; i < 5; ++i) {
            short8 a = *(const short8*)&WcB[frm][i*32 + kg*8];
            acc0 = __builtin_amdgcn_mfma_f32_16x16x32_bf16(a, g0[i], acc0, 0, 0, 0);
            acc1 = __builtin_amdgcn_mfma_f32_16x16x32_bf16(a, g1[i], acc1, 0, 0, 0);
        }
        float* ob = out + ((size_t)(bn*NM + m0))*128;
        #pragma unroll
        for (int r = 0; r < 4; ++r) {
            int m = kg*4 + r;
            ob[m*128 + e0]      = acc0[r];
            ob[m*128 + e0 + 16] = acc1[r];
        }
    }
}

extern "C" void kernel_launch(void* const* d_in, const int* in_sizes, int n_in,
                              void* d_out, int out_size, void* d_ws, size_t ws_size,
                              hipStream_t stream) {
    const float* agent = (const float*)d_in[0];
    const float* lane  = (const float*)d_in[1];
    const float* We = (const float*)d_in[2];
    const float* be = (const float*)d_in[3];
    const float* Wa = (const float*)d_in[4];
    const float* ba = (const float*)d_in[5];
    const float* pe = (const float*)d_in[6];
    const float* Wq = (const float*)d_in[7];
    const float* bq = (const float*)d_in[8];
    const float* Wk = (const float*)d_in[9];
    const float* bk = (const float*)d_in[10];
    const float* Wv = (const float*)d_in[11];
    const float* bv = (const float*)d_in[12];
    const float* Wo = (const float*)d_in[13];
    const float* bo = (const float*)d_in[14];
    const float* Wp = (const float*)d_in[15];
    const float* bp = (const float*)d_in[16];
    float* ws  = (float*)d_ws;
    float* out = (float*)d_out;

    hipLaunchKernelGGL(k_pre, dim3(128), dim3(256), 0, stream,
                       agent, We, be, Wa, ba, pe, Wq, bq, Wk, bk, Wv, bv,
                       Wo, bo, Wp, bp, ws);
    hipLaunchKernelGGL(k_main, dim3(NB*NN*4), dim3(256), 0, stream,
                       agent, lane, ws, out);
}

// Round 8
// 20.697 us; speedup vs baseline: 3.7501x; 1.2347x over previous
//
#include <hip/hip_runtime.h>
#include <hip/hip_bf16.h>

#define L_ 30
#define NB 2
#define NN 64
#define NM 64
#define MCH 16

// ws float offsets
#define O_WOP  0        // 128x128
#define O_CVP  16384    // 30x128  CV' = pesum@Wv + bv
#define O_WEWV 20224    // 4x128
#define O_WAWQ 20736    // 12x128
#define O_BQQ  22272    // 128
#define O_CK   22400    // 30x128
#define O_WEWK 26240    // 4x128
#define O_BOP  26752    // 128
#define O_QS   26880    // 128x128 (q / sqrt(dh))
#define O_GT   43264    // ushort[128][168] transposed G (rows e, cols k)

typedef __attribute__((ext_vector_type(8))) short short8;
typedef __attribute__((ext_vector_type(4))) float f32x4;

__device__ __forceinline__ unsigned short f2b(float v) {
    union { float f; unsigned int u; } x; x.f = v;
    unsigned int u = x.u + 0x7FFFu + ((x.u >> 16) & 1u);
    return (unsigned short)(u >> 16);
}
__device__ __forceinline__ float dot4(float4 a, float4 b) {
    return a.x*b.x + a.y*b.y + a.z*b.z + a.w*b.w;
}

// Stage A: independent products, thread-per-output, e=lane (coalesced), no LDS.
// blocks: [0,64) Wop | [64,79) CV' | [79,94) Ck | [94,96) WeWv | [96,98) WeWk
//         | [98,104) WaWq | 104 bqq
__global__ __launch_bounds__(256)
void kA(const float* __restrict__ We,  const float* __restrict__ be,
        const float* __restrict__ Wa,  const float* __restrict__ ba,
        const float* __restrict__ pe,
        const float* __restrict__ Wq,  const float* __restrict__ bq,
        const float* __restrict__ Wk,  const float* __restrict__ bk,
        const float* __restrict__ Wv,  const float* __restrict__ bv,
        const float* __restrict__ Wo,  const float* __restrict__ Wp,
        float* __restrict__ ws) {
    const int t = threadIdx.x;
    const int b = blockIdx.x;
    const int e = t & 127;
    const int rr = t >> 7;

    if (b < 64) {                       // Wop[d][e] = Wo[d] @ Wp[:,e]
        const int d = 2*b + rr;
        const float* wo = Wo + d*128;
        float acc = 0.f;
        #pragma unroll 8
        for (int x = 0; x < 128; ++x) acc += wo[x] * Wp[x*128 + e];
        ws[O_WOP + d*128 + e] = acc;
    } else if (b < 79) {                // CV'[l][c] = (be+pe_l) @ Wv[:,c] + bv[c]
        const int l = 2*(b-64) + rr;
        const float* pl = pe + l*128;
        float acc = bv[e];
        #pragma unroll 8
        for (int d = 0; d < 128; ++d) acc += (be[d] + pl[d]) * Wv[d*128 + e];
        ws[O_CVP + l*128 + e] = acc;
    } else if (b < 94) {                // Ck[l][e] = (be+pe_l) @ Wk[:,e] + bk[e]
        const int l = 2*(b-79) + rr;
        const float* pl = pe + l*128;
        float acc = bk[e];
        #pragma unroll 8
        for (int d = 0; d < 128; ++d) acc += (be[d] + pl[d]) * Wk[d*128 + e];
        ws[O_CK + l*128 + e] = acc;
    } else if (b < 96) {                // WeWv[j][c]
        const int j = 2*(b-94) + rr;
        const float* wj = We + j*128;
        float acc = 0.f;
        #pragma unroll 8
        for (int d = 0; d < 128; ++d) acc += wj[d] * Wv[d*128 + e];
        ws[O_WEWV + j*128 + e] = acc;
    } else if (b < 98) {                // WeWk[j][e]
        const int j = 2*(b-96) + rr;
        const float* wj = We + j*128;
        float acc = 0.f;
        #pragma unroll 8
        for (int d = 0; d < 128; ++d) acc += wj[d] * Wk[d*128 + e];
        ws[O_WEWK + j*128 + e] = acc;
    } else if (b < 104) {               // WaWq[f][e]
        const int f = 2*(b-98) + rr;
        const float* wf = Wa + f*128;
        float acc = 0.f;
        #pragma unroll 8
        for (int d = 0; d < 128; ++d) acc += wf[d] * Wq[d*128 + e];
        ws[O_WAWQ + f*128 + e] = acc;
    } else {                            // bqq[e] = ba @ Wq[:,e] + bq[e]
        if (t < 128) {
            float acc = bq[e];
            #pragma unroll 8
            for (int d = 0; d < 128; ++d) acc += ba[d] * Wq[d*128 + e];
            ws[O_BQQ + e] = acc;
        }
    }
}

// Stage B: needs Wop/CV'/WeWv/WaWq/bqq. Thread-per-output, e=lane, no LDS.
// blocks: [0,68) G rows (pairs) | [68,132) qs (r pairs) | 132 bop | 133 GT pad
__global__ __launch_bounds__(256)
void kB(const float* __restrict__ agent,
        const float* __restrict__ bo, const float* __restrict__ bp,
        float* __restrict__ ws) {
    const int t = threadIdx.x;
    const int b = blockIdx.x;
    const int e = t & 127;
    const int rr = t >> 7;
    unsigned short* GT = (unsigned short*)(ws + O_GT);

    if (b < 68) {                       // G row k: P (k<16) or D (k>=16)
        const int k = 2*b + rr;
        const float* scal;
        int h;
        if (k < 16) { h = k >> 2; scal = ws + O_WEWV + (k & 3)*128 + h*32; }
        else { int r = k - 16; h = r / 30; int l = r - h*30;
               scal = ws + O_CVP + l*128 + h*32; }
        const float* wop = ws + O_WOP + (h*32)*128 + e;
        float acc = 0.f;
        #pragma unroll 8
        for (int c = 0; c < 32; ++c) acc += scal[c] * wop[c*128];
        GT[e*168 + k] = f2b(acc);
    } else if (b < 132) {               // qs[r][e]
        const int r = 2*(b-68) + rr;
        const float* ag = agent + r*16;
        const float* wq = ws + O_WAWQ;
        float acc = ws[O_BQQ + e];
        acc += ag[2] * wq[e];
        #pragma unroll
        for (int f = 1; f < 12; ++f) acc += ag[4+f] * wq[f*128 + e];
        ws[O_QS + r*128 + e] = acc * 0.17677669529663687f;
    } else if (b == 132) {              // bop[e] = bo @ Wop[:,e] + bp[e]
        if (t < 128) {
            float acc = bp[e];
            #pragma unroll 8
            for (int c = 0; c < 128; ++c) acc += bo[c] * ws[O_WOP + c*128 + e];
            ws[O_BOP + e] = acc;
        }
    } else {                            // GT pad rows 136..167 -> 0
        for (int idx = t; idx < 32*128; idx += 256) {
            int row = 136 + (idx >> 7);
            GT[(idx & 127)*168 + row] = 0;
        }
    }
}

// 512 blocks. 3 phases / 2 barriers; parallel softmax fused with scores + we4.
__global__ __launch_bounds__(256)
void k_main(const float* __restrict__ agent, const float* __restrict__ lane,
            const float* __restrict__ ws, float* __restrict__ out) {

    __shared__ __align__(16) float ScE[16][124];              // edges f32 [m][l*4+j]
    __shared__ __align__(16) unsigned short WcB[16][168];     // bf16: [0..16) we4, [16..136) w
    __shared__ __align__(16) float uc_s[136];                 // [0..16)=u, [16..136)=c

    const int t = threadIdx.x;
    const int bid = blockIdx.x;
    const int bn = bid >> 2;
    const int m0 = (bid & 3) * MCH;
    const int b = bn >> 6;

    // ---- phase 0: G/bias prefetch (regs) + u/c dots + edge geometry + WcB pad ----
    const unsigned short* GT = (const unsigned short*)(ws + O_GT);
    const int lane_id = t & 63;
    const int wv = t >> 6;
    const int frm = lane_id & 15;
    const int kg  = lane_id >> 4;
    const int e0 = wv*32 + frm;
    short8 g0[5], g1[5];
    #pragma unroll
    for (int i = 0; i < 5; ++i) {
        g0[i] = *(const short8*)&GT[(size_t)e0*168 + i*32 + kg*8];
        g1[i] = *(const short8*)&GT[(size_t)(e0+16)*168 + i*32 + kg*8];
    }
    const float bb0 = ws[O_BOP + e0];
    const float bb1 = ws[O_BOP + e0 + 16];

    for (int i = t; i < 16*24; i += 256) {
        int m = i / 24;
        WcB[m][136 + (i - m*24)] = 0;
    }
    if (t < 136) {
        if (t < 16) {
            int h = t >> 2, j = t & 3;
            const float4* x = (const float4*)(ws + O_WEWK + j*128 + h*32);
            const float4* y = (const float4*)(ws + O_QS + bn*128 + h*32);
            float a = 0.f;
            #pragma unroll
            for (int i = 0; i < 8; ++i) a += dot4(x[i], y[i]);
            uc_s[t] = a;
        } else {
            int r = t - 16; int h = r/30, l = r - h*30;
            const float4* x = (const float4*)(ws + O_CK + l*128 + h*32);
            const float4* y = (const float4*)(ws + O_QS + bn*128 + h*32);
            float a = 0.f;
            #pragma unroll
            for (int i = 0; i < 8; ++i) a += dot4(x[i], y[i]);
            uc_s[t] = a;
        }
    }
    const float ax  = agent[bn*16+0], ay = agent[bn*16+1];
    const float as_ = agent[bn*16+3], ac = agent[bn*16+4];
    const float f1 = (ax==0.f && ay==0.f && as_==0.f && ac==0.f) ? 0.f : 1.f;
    for (int job = t; job < MCH*30; job += 256) {
        int m = job / 30, l = job - m*30;
        const float* lp = lane + (size_t)((b*NM + m0 + m)*L_ + l)*4;
        float4 lv = *(const float4*)lp;
        float f2 = (lv.x==0.f && lv.y==0.f && lv.z==0.f && lv.w==0.f) ? 0.f : 1.f;
        float f = f1 * f2;
        float dx = lv.x - ax, dy = lv.y - ay;
        float4 ev;
        ev.x = (ac*dx + as_*dy) * 0.1f * f;
        ev.y = (ac*dy - as_*dx) * 0.1f * f;
        ev.z = (lv.z*ac - lv.w*as_) * f;
        ev.w = (lv.w*ac + lv.z*as_) * f;
        *(float4*)&ScE[m][l*4] = ev;
    }
    __syncthreads();

    // ---- phase 1: scores + 4-lane softmax + fused we4 ----
    {
        const int m = t >> 4, hh = (t >> 2) & 3, s = t & 3;
        float4 u4 = *(const float4*)&uc_s[hh*4];
        float4 e4[8];
        float sc[8];
        float mx = -1e30f;
        #pragma unroll
        for (int k = 0; k < 8; ++k) {
            int l = s + 4*k;
            if (l < 30) {
                e4[k] = *(const float4*)&ScE[m][l*4];
                sc[k] = e4[k].x*u4.x + e4[k].y*u4.y + e4[k].z*u4.z + e4[k].w*u4.w
                      + uc_s[16 + hh*30 + l];
            } else {
                e4[k] = make_float4(0.f,0.f,0.f,0.f);
                sc[k] = -1e30f;
            }
            mx = fmaxf(mx, sc[k]);
        }
        mx = fmaxf(mx, __shfl_xor(mx, 1, 64));
        mx = fmaxf(mx, __shfl_xor(mx, 2, 64));
        float sum = 0.f;
        float wvv[8];
        #pragma unroll
        for (int k = 0; k < 8; ++k) {
            float evv = __expf(sc[k] - mx);
            evv = (s + 4*k < 30) ? evv : 0.f;
            wvv[k] = evv; sum += evv;
        }
        sum += __shfl_xor(sum, 1, 64);
        sum += __shfl_xor(sum, 2, 64);
        const float inv = 1.f / sum;
        float4 p = make_float4(0.f,0.f,0.f,0.f);
        #pragma unroll
        for (int k = 0; k < 8; ++k) {
            int l = s + 4*k;
            if (l < 30) {
                float w = wvv[k] * inv;
                WcB[m][16 + hh*30 + l] = f2b(w);
                p.x += w * e4[k].x; p.y += w * e4[k].y;
                p.z += w * e4[k].z; p.w += w * e4[k].w;
            }
        }
        p.x += __shfl_xor(p.x, 1, 64); p.y += __shfl_xor(p.y, 1, 64);
        p.z += __shfl_xor(p.z, 1, 64); p.w += __shfl_xor(p.w, 1, 64);
        p.x += __shfl_xor(p.x, 2, 64); p.y += __shfl_xor(p.y, 2, 64);
        p.z += __shfl_xor(p.z, 2, 64); p.w += __shfl_xor(p.w, 2, 64);
        float mine = (s == 0) ? p.x : (s == 1) ? p.y : (s == 2) ? p.z : p.w;
        WcB[m][hh*4 + s] = f2b(mine);
    }
    __syncthreads();

    // ---- phase 2: OUT[16x128] = WcB[16x160] @ G[160x128] via MFMA ----
    {
        f32x4 acc0 = {bb0, bb0, bb0, bb0};
        f32x4 acc1 = {bb1, bb1, bb1, bb1};
        #pragma unroll
        for (int i = 0; i < 5; ++i) {
            short8 a = *(const short8*)&WcB[frm][i*32 + kg*8];
            acc0 = __builtin_amdgcn_mfma_f32_16x16x32_bf16(a, g0[i], acc0, 0, 0, 0);
            acc1 = __builtin_amdgcn_mfma_f32_16x16x32_bf16(a, g1[i], acc1, 0, 0, 0);
        }
        float* ob = out + ((size_t)(bn*NM + m0))*128;
        #pragma unroll
        for (int r = 0; r < 4; ++r) {
            int m = kg*4 + r;
            ob[m*128 + e0]      = acc0[r];
            ob[m*128 + e0 + 16] = acc1[r];
        }
    }
}

extern "C" void kernel_launch(void* const* d_in, const int* in_sizes, int n_in,
                              void* d_out, int out_size, void* d_ws, size_t ws_size,
                              hipStream_t stream) {
    const float* agent = (const float*)d_in[0];
    const float* lane  = (const float*)d_in[1];
    const float* We = (const float*)d_in[2];
    const float* be = (const float*)d_in[3];
    const float* Wa = (const float*)d_in[4];
    const float* ba = (const float*)d_in[5];
    const float* pe = (const float*)d_in[6];
    const float* Wq = (const float*)d_in[7];
    const float* bq = (const float*)d_in[8];
    const float* Wk = (const float*)d_in[9];
    const float* bk = (const float*)d_in[10];
    const float* Wv = (const float*)d_in[11];
    const float* bv = (const float*)d_in[12];
    const float* Wo = (const float*)d_in[13];
    const float* bo = (const float*)d_in[14];
    const float* Wp = (const float*)d_in[15];
    const float* bp = (const float*)d_in[16];
    float* ws  = (float*)d_ws;
    float* out = (float*)d_out;

    hipLaunchKernelGGL(kA, dim3(105), dim3(256), 0, stream,
                       We, be, Wa, ba, pe, Wq, bq, Wk, bk, Wv, bv, Wo, Wp, ws);
    hipLaunchKernelGGL(kB, dim3(134), dim3(256), 0, stream, agent, bo, bp, ws);
    hipLaunchKernelGGL(k_main, dim3(NB*NN*4), dim3(256), 0, stream,
                       agent, lane, ws, out);
}

// Round 9
// 19.910 us; speedup vs baseline: 3.8984x; 1.0395x over previous
//
#include <hip/hip_runtime.h>
#include <hip/hip_bf16.h>

#define L_ 30
#define NB 2
#define NN 64
#define NM 64
#define MCH 16

// ws float offsets
#define O_WOP  0        // 128x128
#define O_CVP  16384    // 30x128  CV' = (be+pe)@Wv + bv
#define O_WEWV 20224    // 4x128
#define O_WAWQ 20736    // 12x128
#define O_BQQ  22272    // 128
#define O_CK   22400    // 30x128
#define O_WEWK 26240    // 4x128
#define O_BOP  26752    // 128
#define O_QS   26880    // 128x128 (q / sqrt(dh))
#define O_GT   43264    // ushort[128][168] transposed G (rows e, cols k)

typedef __attribute__((ext_vector_type(8))) short short8;
typedef __attribute__((ext_vector_type(4))) float f32x4;

__device__ __forceinline__ unsigned short f2b(float v) {
    union { float f; unsigned int u; } x; x.f = v;
    unsigned int u = x.u + 0x7FFFu + ((x.u >> 16) & 1u);
    return (unsigned short)(u >> 16);
}
__device__ __forceinline__ float dot4(float4 a, float4 b) {
    return a.x*b.x + a.y*b.y + a.z*b.z + a.w*b.w;
}

// Stage A: independent products, thread-per-output, e=lane (coalesced), no LDS.
// unroll 32 => 32 outstanding L2 loads (4 dependent batches, not 16).
// blocks: [0,64) Wop | [64,79) CV' | [79,94) Ck | [94,96) WeWv | [96,98) WeWk
//         | [98,104) WaWq | 104: bqq (t<128) + bop (t>=128)
__global__ __launch_bounds__(256)
void kA(const float* __restrict__ We,  const float* __restrict__ be,
        const float* __restrict__ Wa,  const float* __restrict__ ba,
        const float* __restrict__ pe,
        const float* __restrict__ Wq,  const float* __restrict__ bq,
        const float* __restrict__ Wk,  const float* __restrict__ bk,
        const float* __restrict__ Wv,  const float* __restrict__ bv,
        const float* __restrict__ Wo,  const float* __restrict__ bo,
        const float* __restrict__ Wp,  const float* __restrict__ bp,
        float* __restrict__ ws) {
    const int t = threadIdx.x;
    const int b = blockIdx.x;
    const int e = t & 127;
    const int rr = t >> 7;

    if (b < 64) {                       // Wop[d][e] = Wo[d] @ Wp[:,e]
        const int d = 2*b + rr;
        const float* wo = Wo + d*128;
        float acc = 0.f;
        #pragma unroll 32
        for (int x = 0; x < 128; ++x) acc += wo[x] * Wp[x*128 + e];
        ws[O_WOP + d*128 + e] = acc;
    } else if (b < 79) {                // CV'[l][c] = (be+pe_l) @ Wv[:,c] + bv[c]
        const int l = 2*(b-64) + rr;
        const float* pl = pe + l*128;
        float acc = bv[e];
        #pragma unroll 32
        for (int d = 0; d < 128; ++d) acc += (be[d] + pl[d]) * Wv[d*128 + e];
        ws[O_CVP + l*128 + e] = acc;
    } else if (b < 94) {                // Ck[l][e] = (be+pe_l) @ Wk[:,e] + bk[e]
        const int l = 2*(b-79) + rr;
        const float* pl = pe + l*128;
        float acc = bk[e];
        #pragma unroll 32
        for (int d = 0; d < 128; ++d) acc += (be[d] + pl[d]) * Wk[d*128 + e];
        ws[O_CK + l*128 + e] = acc;
    } else if (b < 96) {                // WeWv[j][c]
        const int j = 2*(b-94) + rr;
        const float* wj = We + j*128;
        float acc = 0.f;
        #pragma unroll 32
        for (int d = 0; d < 128; ++d) acc += wj[d] * Wv[d*128 + e];
        ws[O_WEWV + j*128 + e] = acc;
    } else if (b < 98) {                // WeWk[j][e]
        const int j = 2*(b-96) + rr;
        const float* wj = We + j*128;
        float acc = 0.f;
        #pragma unroll 32
        for (int d = 0; d < 128; ++d) acc += wj[d] * Wk[d*128 + e];
        ws[O_WEWK + j*128 + e] = acc;
    } else if (b < 104) {               // WaWq[f][e]
        const int f = 2*(b-98) + rr;
        const float* wf = Wa + f*128;
        float acc = 0.f;
        #pragma unroll 32
        for (int d = 0; d < 128; ++d) acc += wf[d] * Wq[d*128 + e];
        ws[O_WAWQ + f*128 + e] = acc;
    } else {
        if (rr == 0) {                  // bqq[e] = ba @ Wq[:,e] + bq[e]
            float acc = bq[e];
            #pragma unroll 32
            for (int d = 0; d < 128; ++d) acc += ba[d] * Wq[d*128 + e];
            ws[O_BQQ + e] = acc;
        } else {                        // bop[e] = bo @ Wp[:,e] + bp[e]   (FIXED)
            float acc = bp[e];
            #pragma unroll 32
            for (int d = 0; d < 128; ++d) acc += bo[d] * Wp[d*128 + e];
            ws[O_BOP + e] = acc;
        }
    }
}

// Stage B: needs Wop/CV'/WeWv/WaWq/bqq. Thread-per-output, e=lane, no LDS.
// blocks: [0,68) G rows (pairs) | [68,132) qs (r pairs) | 132: GT pad
__global__ __launch_bounds__(256)
void kB(const float* __restrict__ agent, float* __restrict__ ws) {
    const int t = threadIdx.x;
    const int b = blockIdx.x;
    const int e = t & 127;
    const int rr = t >> 7;
    unsigned short* GT = (unsigned short*)(ws + O_GT);

    if (b < 68) {                       // G row k: P (k<16) or D (k>=16)
        const int k = 2*b + rr;
        const float* scal;
        int h;
        if (k < 16) { h = k >> 2; scal = ws + O_WEWV + (k & 3)*128 + h*32; }
        else { int r = k - 16; h = r / 30; int l = r - h*30;
               scal = ws + O_CVP + l*128 + h*32; }
        const float* wop = ws + O_WOP + (h*32)*128 + e;
        float acc = 0.f;
        #pragma unroll
        for (int c = 0; c < 32; ++c) acc += scal[c] * wop[c*128];
        GT[e*168 + k] = f2b(acc);
    } else if (b < 132) {               // qs[r][e]
        const int r = 2*(b-68) + rr;
        const float* ag = agent + r*16;
        const float* wq = ws + O_WAWQ;
        float acc = ws[O_BQQ + e];
        acc += ag[2] * wq[e];
        #pragma unroll
        for (int f = 1; f < 12; ++f) acc += ag[4+f] * wq[f*128 + e];
        ws[O_QS + r*128 + e] = acc * 0.17677669529663687f;
    } else {                            // GT pad rows 136..167 -> 0
        for (int idx = t; idx < 32*128; idx += 256) {
            int row = 136 + (idx >> 7);
            GT[(idx & 127)*168 + row] = 0;
        }
    }
}

// 512 blocks. 3 phases / 2 barriers; parallel softmax fused with scores + we4.
__global__ __launch_bounds__(256)
void k_main(const float* __restrict__ agent, const float* __restrict__ lane,
            const float* __restrict__ ws, float* __restrict__ out) {

    __shared__ __align__(16) float ScE[16][124];              // edges f32 [m][l*4+j]
    __shared__ __align__(16) unsigned short WcB[16][168];     // bf16: [0..16) we4, [16..136) w
    __shared__ __align__(16) float uc_s[136];                 // [0..16)=u, [16..136)=c

    const int t = threadIdx.x;
    const int bid = blockIdx.x;
    const int bn = bid >> 2;
    const int m0 = (bid & 3) * MCH;
    const int b = bn >> 6;

    // ---- phase 0: G/bias prefetch (regs) + u/c dots + edge geometry + WcB pad ----
    const unsigned short* GT = (const unsigned short*)(ws + O_GT);
    const int lane_id = t & 63;
    const int wv = t >> 6;
    const int frm = lane_id & 15;
    const int kg  = lane_id >> 4;
    const int e0 = wv*32 + frm;
    short8 g0[5], g1[5];
    #pragma unroll
    for (int i = 0; i < 5; ++i) {
        g0[i] = *(const short8*)&GT[(size_t)e0*168 + i*32 + kg*8];
        g1[i] = *(const short8*)&GT[(size_t)(e0+16)*168 + i*32 + kg*8];
    }
    const float bb0 = ws[O_BOP + e0];
    const float bb1 = ws[O_BOP + e0 + 16];

    for (int i = t; i < 16*24; i += 256) {
        int m = i / 24;
        WcB[m][136 + (i - m*24)] = 0;
    }
    if (t < 136) {
        if (t < 16) {
            int h = t >> 2, j = t & 3;
            const float4* x = (const float4*)(ws + O_WEWK + j*128 + h*32);
            const float4* y = (const float4*)(ws + O_QS + bn*128 + h*32);
            float a = 0.f;
            #pragma unroll
            for (int i = 0; i < 8; ++i) a += dot4(x[i], y[i]);
            uc_s[t] = a;
        } else {
            int r = t - 16; int h = r/30, l = r - h*30;
            const float4* x = (const float4*)(ws + O_CK + l*128 + h*32);
            const float4* y = (const float4*)(ws + O_QS + bn*128 + h*32);
            float a = 0.f;
            #pragma unroll
            for (int i = 0; i < 8; ++i) a += dot4(x[i], y[i]);
            uc_s[t] = a;
        }
    }
    const float ax  = agent[bn*16+0], ay = agent[bn*16+1];
    const float as_ = agent[bn*16+3], ac = agent[bn*16+4];
    const float f1 = (ax==0.f && ay==0.f && as_==0.f && ac==0.f) ? 0.f : 1.f;
    for (int job = t; job < MCH*30; job += 256) {
        int m = job / 30, l = job - m*30;
        const float* lp = lane + (size_t)((b*NM + m0 + m)*L_ + l)*4;
        float4 lv = *(const float4*)lp;
        float f2 = (lv.x==0.f && lv.y==0.f && lv.z==0.f && lv.w==0.f) ? 0.f : 1.f;
        float f = f1 * f2;
        float dx = lv.x - ax, dy = lv.y - ay;
        float4 ev;
        ev.x = (ac*dx + as_*dy) * 0.1f * f;
        ev.y = (ac*dy - as_*dx) * 0.1f * f;
        ev.z = (lv.z*ac - lv.w*as_) * f;
        ev.w = (lv.w*ac + lv.z*as_) * f;
        *(float4*)&ScE[m][l*4] = ev;
    }
    __syncthreads();

    // ---- phase 1: scores + 4-lane softmax + fused we4 ----
    {
        const int m = t >> 4, hh = (t >> 2) & 3, s = t & 3;
        float4 u4 = *(const float4*)&uc_s[hh*4];
        float4 e4[8];
        float sc[8];
        float mx = -1e30f;
        #pragma unroll
        for (int k = 0; k < 8; ++k) {
            int l = s + 4*k;
            if (l < 30) {
                e4[k] = *(const float4*)&ScE[m][l*4];
                sc[k] = e4[k].x*u4.x + e4[k].y*u4.y + e4[k].z*u4.z + e4[k].w*u4.w
                      + uc_s[16 + hh*30 + l];
            } else {
                e4[k] = make_float4(0.f,0.f,0.f,0.f);
                sc[k] = -1e30f;
            }
            mx = fmaxf(mx, sc[k]);
        }
        mx = fmaxf(mx, __shfl_xor(mx, 1, 64));
        mx = fmaxf(mx, __shfl_xor(mx, 2, 64));
        float sum = 0.f;
        float wvv[8];
        #pragma unroll
        for (int k = 0; k < 8; ++k) {
            float evv = __expf(sc[k] - mx);
            evv = (s + 4*k < 30) ? evv : 0.f;
            wvv[k] = evv; sum += evv;
        }
        sum += __shfl_xor(sum, 1, 64);
        sum += __shfl_xor(sum, 2, 64);
        const float inv = 1.f / sum;
        float4 p = make_float4(0.f,0.f,0.f,0.f);
        #pragma unroll
        for (int k = 0; k < 8; ++k) {
            int l = s + 4*k;
            if (l < 30) {
                float w = wvv[k] * inv;
                WcB[m][16 + hh*30 + l] = f2b(w);
                p.x += w * e4[k].x; p.y += w * e4[k].y;
                p.z += w * e4[k].z; p.w += w * e4[k].w;
            }
        }
        p.x += __shfl_xor(p.x, 1, 64); p.y += __shfl_xor(p.y, 1, 64);
        p.z += __shfl_xor(p.z, 1, 64); p.w += __shfl_xor(p.w, 1, 64);
        p.x += __shfl_xor(p.x, 2, 64); p.y += __shfl_xor(p.y, 2, 64);
        p.z += __shfl_xor(p.z, 2, 64); p.w += __shfl_xor(p.w, 2, 64);
        float mine = (s == 0) ? p.x : (s == 1) ? p.y : (s == 2) ? p.z : p.w;
        WcB[m][hh*4 + s] = f2b(mine);
    }
    __syncthreads();

    // ---- phase 2: OUT[16x128] = WcB[16x160] @ G[160x128] via MFMA ----
    {
        f32x4 acc0 = {bb0, bb0, bb0, bb0};
        f32x4 acc1 = {bb1, bb1, bb1, bb1};
        #pragma unroll
        for (int i = 0; i < 5; ++i) {
            short8 a = *(const short8*)&WcB[frm][i*32 + kg*8];
            acc0 = __builtin_amdgcn_mfma_f32_16x16x32_bf16(a, g0[i], acc0, 0, 0, 0);
            acc1 = __builtin_amdgcn_mfma_f32_16x16x32_bf16(a, g1[i], acc1, 0, 0, 0);
        }
        float* ob = out + ((size_t)(bn*NM + m0))*128;
        #pragma unroll
        for (int r = 0; r < 4; ++r) {
            int m = kg*4 + r;
            ob[m*128 + e0]      = acc0[r];
            ob[m*128 + e0 + 16] = acc1[r];
        }
    }
}

extern "C" void kernel_launch(void* const* d_in, const int* in_sizes, int n_in,
                              void* d_out, int out_size, void* d_ws, size_t ws_size,
                              hipStream_t stream) {
    const float* agent = (const float*)d_in[0];
    const float* lane  = (const float*)d_in[1];
    const float* We = (const float*)d_in[2];
    const float* be = (const float*)d_in[3];
    const float* Wa = (const float*)d_in[4];
    const float* ba = (const float*)d_in[5];
    const float* pe = (const float*)d_in[6];
    const float* Wq = (const float*)d_in[7];
    const float* bq = (const float*)d_in[8];
    const float* Wk = (const float*)d_in[9];
    const float* bk = (const float*)d_in[10];
    const float* Wv = (const float*)d_in[11];
    const float* bv = (const float*)d_in[12];
    const float* Wo = (const float*)d_in[13];
    const float* bo = (const float*)d_in[14];
    const float* Wp = (const float*)d_in[15];
    const float* bp = (const float*)d_in[16];
    float* ws  = (float*)d_ws;
    float* out = (float*)d_out;

    hipLaunchKernelGGL(kA, dim3(105), dim3(256), 0, stream,
                       We, be, Wa, ba, pe, Wq, bq, Wk, bk, Wv, bv, Wo, bo, Wp, bp, ws);
    hipLaunchKernelGGL(kB, dim3(133), dim3(256), 0, stream, agent, ws);
    hipLaunchKernelGGL(k_main, dim3(NB*NN*4), dim3(256), 0, stream,
                       agent, lane, ws, out);
}

// Round 10
// 18.136 us; speedup vs baseline: 4.2797x; 1.0978x over previous
//
#include <hip/hip_runtime.h>
#include <hip/hip_bf16.h>

#define L_ 30
#define NB 2
#define NN 64
#define NM 64
#define MCH 16

// ws float offsets
#define O_WAWQ 0        // 12x128
#define O_BQQ  1536     // 128
#define O_CK   1664     // 30x128
#define O_WEWK 5504     // 4x128
#define O_BOP  6016     // 128
#define O_SCT  6144     // ushort[128 c][168 k]  scal^T (masked-dense, bf16)
#define O_WOPT 16896    // ushort[128 e][128 c]  Wop^T (bf16)

typedef __attribute__((ext_vector_type(8))) short short8;
typedef __attribute__((ext_vector_type(4))) float f32x4;

__device__ __forceinline__ unsigned short f2b(float v) {
    union { float f; unsigned int u; } x; x.f = v;
    unsigned int u = x.u + 0x7FFFu + ((x.u >> 16) & 1u);
    return (unsigned short)(u >> 16);
}
__device__ __forceinline__ float dot4(float4 a, float4 b) {
    return a.x*b.x + a.y*b.y + a.z*b.z + a.w*b.w;
}

// kA: ALL weight-only products, depth-1, thread-per-output, e=lane coalesced.
// blocks: [0,64) WopT (d-pair) | [64,79) CV'->scalT D-rows (l-pair)
//         | [79,81) WeWv->scalT P-rows (j-pair) | [81,96) Ck | [96,98) WeWk
//         | [98,104) WaWq | 104 bqq/bop | 105 scalT pad cols 136..167
__global__ __launch_bounds__(256)
void kA(const float* __restrict__ We,  const float* __restrict__ be,
        const float* __restrict__ Wa,  const float* __restrict__ ba,
        const float* __restrict__ pe,
        const float* __restrict__ Wq,  const float* __restrict__ bq,
        const float* __restrict__ Wk,  const float* __restrict__ bk,
        const float* __restrict__ Wv,  const float* __restrict__ bv,
        const float* __restrict__ Wo,  const float* __restrict__ bo,
        const float* __restrict__ Wp,  const float* __restrict__ bp,
        float* __restrict__ ws) {
    const int t = threadIdx.x;
    const int b = blockIdx.x;
    const int e = t & 127;
    const int rr = t >> 7;
    unsigned short* SCT  = (unsigned short*)(ws + O_SCT);
    unsigned short* WOPT = (unsigned short*)(ws + O_WOPT);

    if (b < 64) {                       // WopT[e][d] = Wo[d] @ Wp[:,e]
        const int d = 2*b + rr;
        const float* wo = Wo + d*128;
        float acc = 0.f;
        #pragma unroll 32
        for (int x = 0; x < 128; ++x) acc += wo[x] * Wp[x*128 + e];
        WOPT[e*128 + d] = f2b(acc);
    } else if (b < 79) {                // CV'[l][c]=(be+pe_l)@Wv[:,c]+bv -> scalT D-rows
        const int l = 2*(b-64) + rr;
        const int h = e >> 5;
        const float* pl = pe + l*128;
        float acc = bv[e];
        #pragma unroll 32
        for (int d = 0; d < 128; ++d) acc += (be[d] + pl[d]) * Wv[d*128 + e];
        unsigned short v = f2b(acc);
        #pragma unroll
        for (int hh = 0; hh < 4; ++hh)
            SCT[e*168 + 16 + hh*30 + l] = (hh == h) ? v : (unsigned short)0;
    } else if (b < 81) {                // WeWv[j][c] -> scalT P-rows (no bias)
        const int j = 2*(b-79) + rr;
        const int h = e >> 5;
        const float* wj = We + j*128;
        float acc = 0.f;
        #pragma unroll 32
        for (int d = 0; d < 128; ++d) acc += wj[d] * Wv[d*128 + e];
        unsigned short v = f2b(acc);
        #pragma unroll
        for (int hh = 0; hh < 4; ++hh)
            SCT[e*168 + hh*4 + j] = (hh == h) ? v : (unsigned short)0;
    } else if (b < 96) {                // Ck[l][e] = (be+pe_l)@Wk[:,e]+bk
        const int l = 2*(b-81) + rr;
        const float* pl = pe + l*128;
        float acc = bk[e];
        #pragma unroll 32
        for (int d = 0; d < 128; ++d) acc += (be[d] + pl[d]) * Wk[d*128 + e];
        ws[O_CK + l*128 + e] = acc;
    } else if (b < 98) {                // WeWk[j][e]
        const int j = 2*(b-96) + rr;
        const float* wj = We + j*128;
        float acc = 0.f;
        #pragma unroll 32
        for (int d = 0; d < 128; ++d) acc += wj[d] * Wk[d*128 + e];
        ws[O_WEWK + j*128 + e] = acc;
    } else if (b < 104) {               // WaWq[f][e]
        const int f = 2*(b-98) + rr;
        const float* wf = Wa + f*128;
        float acc = 0.f;
        #pragma unroll 32
        for (int d = 0; d < 128; ++d) acc += wf[d] * Wq[d*128 + e];
        ws[O_WAWQ + f*128 + e] = acc;
    } else if (b == 104) {
        if (rr == 0) {                  // bqq[e] = ba@Wq[:,e] + bq[e]
            float acc = bq[e];
            #pragma unroll 32
            for (int d = 0; d < 128; ++d) acc += ba[d] * Wq[d*128 + e];
            ws[O_BQQ + e] = acc;
        } else {                        // bop[e] = bo@Wp[:,e] + bp[e]
            float acc = bp[e];
            #pragma unroll 32
            for (int d = 0; d < 128; ++d) acc += bo[d] * Wp[d*128 + e];
            ws[O_BOP + e] = acc;
        }
    } else {                            // pad scalT cols 136..167
        for (int i = t; i < 128*32; i += 256) {
            int c = i >> 5, k = 136 + (i & 31);
            SCT[c*168 + k] = 0;
        }
    }
}

// 512 blocks. P0 {frag prefetch, qs, edges} / P1 {u,c} / P2 {scores+softmax+we4}
// / P3 {T = Wc@scalT (MFMA) -> LDS bf16} / P4 {out = T@Wop + bop (MFMA)}
__global__ __launch_bounds__(256)
void k_main(const float* __restrict__ agent, const float* __restrict__ lane,
            const float* __restrict__ ws, float* __restrict__ out) {

    __shared__ __align__(16) float ScE[16][124];              // edges f32 [m][l*4+j]
    __shared__ __align__(16) unsigned short WcB[16][168];     // bf16 A1: we4 | w | pad
    __shared__ __align__(16) unsigned short T_s[16][136];     // bf16 T = Wc@scalT
    __shared__ __align__(16) float uc_s[136];                 // u(16) | c(120)
    __shared__ __align__(16) float qs_s[128];                 // q/sqrt(dh)

    const int t = threadIdx.x;
    const int bid = blockIdx.x;
    const int bn = bid >> 2;
    const int m0 = (bid & 3) * MCH;
    const int b = bn >> 6;

    // ---- P0 ----
    const unsigned short* SCT  = (const unsigned short*)(ws + O_SCT);
    const unsigned short* WOPT = (const unsigned short*)(ws + O_WOPT);
    const int lane_id = t & 63;
    const int wv = t >> 6;
    const int frm = lane_id & 15;
    const int kg  = lane_id >> 4;
    const int e0 = wv*32 + frm;          // col slice: c0 for GEMM1, e0 for GEMM2
    short8 s0[5], s1[5];
    #pragma unroll
    for (int i = 0; i < 5; ++i) {
        s0[i] = *(const short8*)&SCT[e0*168 + i*32 + kg*8];
        s1[i] = *(const short8*)&SCT[(e0+16)*168 + i*32 + kg*8];
    }
    short8 w0[4], w1[4];
    #pragma unroll
    for (int i = 0; i < 4; ++i) {
        w0[i] = *(const short8*)&WOPT[e0*128 + i*32 + kg*8];
        w1[i] = *(const short8*)&WOPT[(e0+16)*128 + i*32 + kg*8];
    }
    const float bb0 = ws[O_BOP + e0];
    const float bb1 = ws[O_BOP + e0 + 16];

    if (t < 128) {                       // qs
        const float* ag = agent + bn*16;
        float acc = ws[O_BQQ + t];
        acc += ag[2] * ws[O_WAWQ + t];
        #pragma unroll
        for (int f = 1; f < 12; ++f) acc += ag[4+f] * ws[O_WAWQ + f*128 + t];
        qs_s[t] = acc * 0.17677669529663687f;
    }
    for (int i = t; i < 16*32; i += 256) {       // WcB pad cols 136..167
        int m = i >> 5;
        WcB[m][136 + (i & 31)] = 0;
    }
    const float ax  = agent[bn*16+0], ay = agent[bn*16+1];
    const float as_ = agent[bn*16+3], ac = agent[bn*16+4];
    const float f1 = (ax==0.f && ay==0.f && as_==0.f && ac==0.f) ? 0.f : 1.f;
    for (int job = t; job < MCH*30; job += 256) {
        int m = job / 30, l = job - m*30;
        const float* lp = lane + (size_t)((b*NM + m0 + m)*L_ + l)*4;
        float4 lv = *(const float4*)lp;
        float f2 = (lv.x==0.f && lv.y==0.f && lv.z==0.f && lv.w==0.f) ? 0.f : 1.f;
        float f = f1 * f2;
        float dx = lv.x - ax, dy = lv.y - ay;
        float4 ev;
        ev.x = (ac*dx + as_*dy) * 0.1f * f;
        ev.y = (ac*dy - as_*dx) * 0.1f * f;
        ev.z = (lv.z*ac - lv.w*as_) * f;
        ev.w = (lv.w*ac + lv.z*as_) * f;
        *(float4*)&ScE[m][l*4] = ev;
    }
    __syncthreads();

    // ---- P1: u (4x4), c (4x30) from qs_s ----
    if (t < 136) {
        float a = 0.f;
        if (t < 16) {
            int h = t >> 2, j = t & 3;
            const float4* x = (const float4*)(ws + O_WEWK + j*128 + h*32);
            const float4* y = (const float4*)&qs_s[h*32];
            #pragma unroll
            for (int i = 0; i < 8; ++i) a += dot4(x[i], y[i]);
        } else {
            int r = t - 16; int h = r/30, l = r - h*30;
            const float4* x = (const float4*)(ws + O_CK + l*128 + h*32);
            const float4* y = (const float4*)&qs_s[h*32];
            #pragma unroll
            for (int i = 0; i < 8; ++i) a += dot4(x[i], y[i]);
        }
        uc_s[t] = a;
    }
    __syncthreads();

    // ---- P2: scores + 4-lane softmax + fused we4 ----
    {
        const int m = t >> 4, hh = (t >> 2) & 3, s = t & 3;
        float4 u4 = *(const float4*)&uc_s[hh*4];
        float4 e4[8];
        float sc[8];
        float mx = -1e30f;
        #pragma unroll
        for (int k = 0; k < 8; ++k) {
            int l = s + 4*k;
            if (l < 30) {
                e4[k] = *(const float4*)&ScE[m][l*4];
                sc[k] = e4[k].x*u4.x + e4[k].y*u4.y + e4[k].z*u4.z + e4[k].w*u4.w
                      + uc_s[16 + hh*30 + l];
            } else {
                e4[k] = make_float4(0.f,0.f,0.f,0.f);
                sc[k] = -1e30f;
            }
            mx = fmaxf(mx, sc[k]);
        }
        mx = fmaxf(mx, __shfl_xor(mx, 1, 64));
        mx = fmaxf(mx, __shfl_xor(mx, 2, 64));
        float sum = 0.f;
        float wvv[8];
        #pragma unroll
        for (int k = 0; k < 8; ++k) {
            float evv = __expf(sc[k] - mx);
            evv = (s + 4*k < 30) ? evv : 0.f;
            wvv[k] = evv; sum += evv;
        }
        sum += __shfl_xor(sum, 1, 64);
        sum += __shfl_xor(sum, 2, 64);
        const float inv = 1.f / sum;
        float4 p = make_float4(0.f,0.f,0.f,0.f);
        #pragma unroll
        for (int k = 0; k < 8; ++k) {
            int l = s + 4*k;
            if (l < 30) {
                float w = wvv[k] * inv;
                WcB[m][16 + hh*30 + l] = f2b(w);
                p.x += w * e4[k].x; p.y += w * e4[k].y;
                p.z += w * e4[k].z; p.w += w * e4[k].w;
            }
        }
        p.x += __shfl_xor(p.x, 1, 64); p.y += __shfl_xor(p.y, 1, 64);
        p.z += __shfl_xor(p.z, 1, 64); p.w += __shfl_xor(p.w, 1, 64);
        p.x += __shfl_xor(p.x, 2, 64); p.y += __shfl_xor(p.y, 2, 64);
        p.z += __shfl_xor(p.z, 2, 64); p.w += __shfl_xor(p.w, 2, 64);
        float mine = (s == 0) ? p.x : (s == 1) ? p.y : (s == 2) ? p.z : p.w;
        WcB[m][hh*4 + s] = f2b(mine);
    }
    __syncthreads();

    // ---- P3: T[16m x 128c] = WcB[16x160] @ scalT-cols (MFMA) -> T_s bf16 ----
    {
        f32x4 a0 = {0.f,0.f,0.f,0.f};
        f32x4 a1 = {0.f,0.f,0.f,0.f};
        #pragma unroll
        for (int i = 0; i < 5; ++i) {
            short8 a = *(const short8*)&WcB[frm][i*32 + kg*8];
            a0 = __builtin_amdgcn_mfma_f32_16x16x32_bf16(a, s0[i], a0, 0, 0, 0);
            a1 = __builtin_amdgcn_mfma_f32_16x16x32_bf16(a, s1[i], a1, 0, 0, 0);
        }
        #pragma unroll
        for (int r = 0; r < 4; ++r) {
            T_s[kg*4 + r][e0]      = f2b(a0[r]);
            T_s[kg*4 + r][e0 + 16] = f2b(a1[r]);
        }
    }
    __syncthreads();

    // ---- P4: OUT[16m x 128e] = T[16x128] @ Wop (MFMA), acc init = bop ----
    {
        f32x4 acc0 = {bb0, bb0, bb0, bb0};
        f32x4 acc1 = {bb1, bb1, bb1, bb1};
        #pragma unroll
        for (int i = 0; i < 4; ++i) {
            short8 a2 = *(const short8*)&T_s[frm][i*32 + kg*8];
            acc0 = __builtin_amdgcn_mfma_f32_16x16x32_bf16(a2, w0[i], acc0, 0, 0, 0);
            acc1 = __builtin_amdgcn_mfma_f32_16x16x32_bf16(a2, w1[i], acc1, 0, 0, 0);
        }
        float* ob = out + ((size_t)(bn*NM + m0))*128;
        #pragma unroll
        for (int r = 0; r < 4; ++r) {
            int m = kg*4 + r;
            ob[m*128 + e0]      = acc0[r];
            ob[m*128 + e0 + 16] = acc1[r];
        }
    }
}

extern "C" void kernel_launch(void* const* d_in, const int* in_sizes, int n_in,
                              void* d_out, int out_size, void* d_ws, size_t ws_size,
                              hipStream_t stream) {
    const float* agent = (const float*)d_in[0];
    const float* lane  = (const float*)d_in[1];
    const float* We = (const float*)d_in[2];
    const float* be = (const float*)d_in[3];
    const float* Wa = (const float*)d_in[4];
    const float* ba = (const float*)d_in[5];
    const float* pe = (const float*)d_in[6];
    const float* Wq = (const float*)d_in[7];
    const float* bq = (const float*)d_in[8];
    const float* Wk = (const float*)d_in[9];
    const float* bk = (const float*)d_in[10];
    const float* Wv = (const float*)d_in[11];
    const float* bv = (const float*)d_in[12];
    const float* Wo = (const float*)d_in[13];
    const float* bo = (const float*)d_in[14];
    const float* Wp = (const float*)d_in[15];
    const float* bp = (const float*)d_in[16];
    float* ws  = (float*)d_ws;
    float* out = (float*)d_out;

    hipLaunchKernelGGL(kA, dim3(106), dim3(256), 0, stream,
                       We, be, Wa, ba, pe, Wq, bq, Wk, bk, Wv, bv, Wo, bo, Wp, bp, ws);
    hipLaunchKernelGGL(k_main, dim3(NB*NN*4), dim3(256), 0, stream,
                       agent, lane, ws, out);
}